// Round 12
// baseline (778.778 us; speedup 1.0000x reference)
//
// rev r12 — ROOT CAUSE FOUND (r11 telemetry): inputs AND output are float32.
// All prior rounds wrote bf16-packed u16 into an f32-validated buffer -> the
// f32 view reads ~0/denormals + untouched upper half -> bit-identical
// absmax = max|ref| for 12 rounds. This round: native f32 end-to-end.
#include <hip/hip_runtime.h>
#include <cstdio>

// ---------------- CSR build (by dst); self-loops appended after real edges ----
__global__ void r12_zero(int* p, int n){
  int t = blockIdx.x*blockDim.x + threadIdx.x;
  if (t < n) p[t] = 0;
}

__global__ void r12_hist(const int* ei, int E, int Ep, int* cnt){
  int t = blockIdx.x*blockDim.x + threadIdx.x;
  if (t >= Ep) return;
  int dst = (t < E) ? ei[E + t] : (t - E);
  atomicAdd(&cnt[dst], 1);
}

__global__ void r12_scan1(const int* in, int n, int* incl, int* bsums){
  __shared__ int tmp[256];
  int t = threadIdx.x; int g = blockIdx.x*256 + t;
  int v = (g < n) ? in[g] : 0;
  tmp[t] = v; __syncthreads();
  for (int off = 1; off < 256; off <<= 1){
    int u = (t >= off) ? tmp[t - off] : 0;
    __syncthreads();
    tmp[t] += u;
    __syncthreads();
  }
  if (g < n) incl[g] = tmp[t];
  if (t == 255) bsums[blockIdx.x] = tmp[255];
}

__global__ void r12_scan2(int* bsums, int nb){
  __shared__ int tmp[256];
  int t = threadIdx.x;
  int v = (t < nb) ? bsums[t] : 0;
  tmp[t] = v; __syncthreads();
  for (int off = 1; off < 256; off <<= 1){
    int u = (t >= off) ? tmp[t - off] : 0;
    __syncthreads();
    tmp[t] += u;
    __syncthreads();
  }
  if (t < nb) bsums[t] = tmp[t];
}

__global__ void r12_scan3(const int* incl, const int* cnt, const int* bsums,
                          int n, int Nnodes, int* offs, int* cursor){
  int t = threadIdx.x; int b = blockIdx.x; int g = b*256 + t;
  if (g >= n) return;
  int add = (b > 0) ? bsums[b-1] : 0;
  int ex = incl[g] - cnt[g] + add;       // exclusive prefix
  offs[g] = ex;
  if (g < Nnodes) cursor[g] = ex;
}

__global__ void r12_fill(const int* ei, int E, int Ep, int* cursor, int* csr_src){
  int t = blockIdx.x*blockDim.x + threadIdx.x;
  if (t >= Ep) return;
  int src, dst;
  if (t < E){ src = ei[t]; dst = ei[E + t]; } else { src = t - E; dst = t - E; }
  int pos = atomicAdd(&cursor[dst], 1);
  csr_src[pos] = src;
}

// ---- GEMM: H[n x 128] = X[n x 128] @ W[128 x 128], all f32 ----
// 4 rows / 256-thread block (one wave per row); 2 KB LDS X-tile. Per k the
// wave reads 64 consecutive float2 of W's row = 512 B coalesced; W (64 KB)
// stays L2-resident across blocks.
__global__ void r12_gemm(const float* __restrict__ X, const float* __restrict__ W,
                         float* __restrict__ H, int nrows){
  __shared__ float xs[4*128];
  int t = threadIdx.x;
  int r0 = blockIdx.x * 4;
  // stage 4 rows (512 f32 = 128 float4)
  if (t < 128){
    int rr = t >> 5, c4 = (t & 31) * 4;
    int row = r0 + rr;
    float4 v = {0.f,0.f,0.f,0.f};
    if (row < nrows) v = *(const float4*)(X + (size_t)row*128 + c4);
    *(float4*)&xs[rr*128 + c4] = v;
  }
  __syncthreads();
  int rloc = t >> 6;            // 0..3 (one wave per row)
  int row  = r0 + rloc;
  int c2   = (t & 63) * 2;      // column pair
  const float* xrow = &xs[rloc*128];
  float a0 = 0.f, a1 = 0.f;
  #pragma unroll 8
  for (int k = 0; k < 128; ++k){
    float2 w = *(const float2*)(W + (size_t)k*128 + c2);
    float xk = xrow[k];
    a0 = fmaf(xk, w.x, a0);
    a1 = fmaf(xk, w.y, a1);
  }
  if (row < nrows){
    float2 o = {a0, a1};
    *(float2*)(H + (size_t)row*128 + c2) = o;
  }
}

// ---- per-node attention dots: AS = h·att_src, AD = h·att_dst (one wave/node) ----
__global__ void r12_dots(const float* __restrict__ H, const float* __restrict__ atts,
                         const float* __restrict__ attd,
                         float* __restrict__ AS, float* __restrict__ AD, int n){
  int wid  = (blockIdx.x*256 + threadIdx.x) >> 6;
  int lane = threadIdx.x & 63;
  if (wid >= n) return;
  float2 hv = ((const float2*)(H + (size_t)wid*128))[lane];
  float2 sv = ((const float2*)atts)[lane];
  float2 dv = ((const float2*)attd)[lane];
  float ps = hv.x*sv.x + hv.y*sv.y;
  float pd = hv.x*dv.x + hv.y*dv.y;
  for (int off = 32; off >= 1; off >>= 1){
    ps += __shfl_xor(ps, off);
    pd += __shfl_xor(pd, off);
  }
  if (lane == 0){ AS[wid] = ps; AD[wid] = pd; }
}

// ---- segment softmax + weighted aggregation (one wave / dst node), f32 ----
__global__ void r12_aggregate(const float* __restrict__ H, const float* __restrict__ AS,
                              const float* __restrict__ AD,
                              const int* __restrict__ offs, const int* __restrict__ csr,
                              const float* __restrict__ bias,
                              const float* __restrict__ gamma_, const float* __restrict__ beta_,
                              const float* __restrict__ mean_, const float* __restrict__ var_,
                              float* __restrict__ outp, int n, int doBN){
  int wid  = (blockIdx.x*256 + threadIdx.x) >> 6;
  int lane = threadIdx.x & 63;
  if (wid >= n) return;
  int beg = offs[wid], end = offs[wid+1];
  float ad = AD[wid];
  // pass 1: segment max (stable softmax, matches reference)
  float m = -3.0e38f;
  for (int k = beg + lane; k < end; k += 64){
    int s = csr[k];
    float e = AS[s] + ad; e = (e > 0.f) ? e : 0.2f*e;
    m = fmaxf(m, e);
  }
  for (int off = 32; off >= 1; off >>= 1) m = fmaxf(m, __shfl_xor(m, off));
  // pass 2: denominator
  float den = 0.f;
  for (int k = beg + lane; k < end; k += 64){
    int s = csr[k];
    float e = AS[s] + ad; e = (e > 0.f) ? e : 0.2f*e;
    den += __expf(e - m);
  }
  for (int off = 32; off >= 1; off >>= 1) den += __shfl_xor(den, off);
  float inv = 1.0f / (den + 1e-16f);
  // pass 3: wave walks edges together; each lane owns 2 feature channels
  float a0 = 0.f, a1 = 0.f;
  for (int k = beg; k < end; ++k){
    int s = csr[k];                                       // wave-uniform
    float e = AS[s] + ad; e = (e > 0.f) ? e : 0.2f*e;
    float al = __expf(e - m) * inv;
    float2 hv = ((const float2*)(H + (size_t)s*128))[lane]; // 512B coalesced/edge
    a0 = fmaf(al, hv.x, a0);
    a1 = fmaf(al, hv.y, a1);
  }
  int c0 = lane*2;
  float v0 = a0 + bias[c0];
  float v1 = a1 + bias[c0+1];
  v0 = fmaxf(v0, 0.f); v1 = fmaxf(v1, 0.f);               // relu
  if (doBN){
    float s0 = gamma_[c0]   * rsqrtf(var_[c0]   + 1e-5f);
    float s1 = gamma_[c0+1] * rsqrtf(var_[c0+1] + 1e-5f);
    v0 = (v0 - mean_[c0])*s0   + beta_[c0];
    v1 = (v1 - mean_[c0+1])*s1 + beta_[c0+1];
  }
  float2 o = {v0, v1};
  ((float2*)(outp + (size_t)wid*128))[lane] = o;
}

extern "C" void kernel_launch(void* const* d_in, const int* in_sizes, int n_in,
                              void* d_out, int out_size, void* d_ws, size_t ws_size,
                              hipStream_t stream){
  const float* x   = (const float*)d_in[0];
  const int*   ei  = (const int*)  d_in[1];
  const float* W1  = (const float*)d_in[2];
  const float* as1 = (const float*)d_in[3];
  const float* ad1 = (const float*)d_in[4];
  const float* b1  = (const float*)d_in[5];
  const float* bng = (const float*)d_in[6];
  const float* bnb = (const float*)d_in[7];
  const float* bnm = (const float*)d_in[8];
  const float* bnv = (const float*)d_in[9];
  const float* W2  = (const float*)d_in[10];
  const float* as2 = (const float*)d_in[11];
  const float* ad2 = (const float*)d_in[12];
  const float* b2  = (const float*)d_in[13];
  float* out = (float*)d_out;

  int N  = in_sizes[0] / 128;
  int E  = in_sizes[1] / 2;
  int Ep = E + N;
  if (N <= 0 || E <= 0) return;

  // workspace (~60 MB of 256 MB): control arrays first, big f32 arrays last
  char* p = (char*)d_ws;
  float* AS     = (float*)p;  p += (size_t)N*4;
  float* AD     = (float*)p;  p += (size_t)N*4;
  int*   cnt    = (int*)  p;  p += (size_t)(N+1)*4;
  int*   offs   = (int*)  p;  p += (size_t)(N+1)*4;
  int*   cursor = (int*)  p;  p += (size_t)N*4;
  int*   bsums  = (int*)  p;  p += 1024;
  int*   csr    = (int*)  p;  p += (size_t)Ep*4;
  float* h      = (float*)p;  p += (size_t)N*128*4;   // 25.6 MB
  float* x2     = (float*)p;  p += (size_t)N*128*4;   // 25.6 MB

  int n1 = N + 1;
  int zb = (n1 + 255)/256;
  int eb = (Ep + 255)/256;
  int sb = (n1 + 255)/256;

  // CSR by dst
  r12_zero <<<zb, 256, 0, stream>>>(cnt, n1);
  r12_hist <<<eb, 256, 0, stream>>>(ei, E, Ep, cnt);
  r12_scan1<<<sb, 256, 0, stream>>>(cnt, n1, offs, bsums);
  r12_scan2<<<1, 256, 0, stream>>>(bsums, sb);
  r12_scan3<<<sb, 256, 0, stream>>>(offs, cnt, bsums, n1, N, offs, cursor);
  r12_fill <<<eb, 256, 0, stream>>>(ei, E, Ep, cursor, csr);

  int gb = (N + 3)/4;   // 4 rows / block
  int wb = (N + 3)/4;   // 4 waves / block

  // layer 1: GAT(hid->hid) -> relu -> BN (fused epilogue) -> x2
  r12_gemm     <<<gb, 256, 0, stream>>>(x, W1, h, N);
  r12_dots     <<<wb, 256, 0, stream>>>(h, as1, ad1, AS, AD, N);
  r12_aggregate<<<wb, 256, 0, stream>>>(h, AS, AD, offs, csr, b1, bng, bnb, bnm, bnv,
                                        x2, N, 1);
  // layer 2: GAT(hid->feat) -> relu -> f32 out
  r12_gemm     <<<gb, 256, 0, stream>>>(x2, W2, h, N);
  r12_dots     <<<wb, 256, 0, stream>>>(h, as2, ad2, AS, AD, N);
  r12_aggregate<<<wb, 256, 0, stream>>>(h, AS, AD, offs, csr, b2, 0, 0, 0, 0,
                                        out, N, 0);

  // capture-gated telemetry: confirm f32 output values land in d_out
  hipStreamCaptureStatus cs = hipStreamCaptureStatusNone;
  hipStreamIsCapturing(stream, &cs);
  if (cs == hipStreamCaptureStatusNone){
    hipStreamSynchronize(stream);
    float ob[4] = {0};
    hipMemcpy(ob, d_out, sizeof(ob), hipMemcpyDeviceToHost);
    fprintf(stderr, "[r12] out_f32 = %g %g %g %g\n", ob[0], ob[1], ob[2], ob[3]);
    fflush(stderr);
  }
}

// Round 13
// 468.383 us; speedup vs baseline: 1.6627x; 1.6627x over previous
//
// rev r13 — first real optimization round (r12 passed: 778 µs, absmax 2e-3).
// rocprof: gemm 190 µs @ VALUBusy 9% (latency-bound, ILP=2) -> register-blocked
// 64x128 tile, 32 acc/thread. aggregate gathers 435 MB f32 -> gather bf16 copy
// of h (dots keeps f32 h so attention logits stay exact).
#include <hip/hip_runtime.h>

typedef unsigned short u16;
typedef unsigned int   u32;

__device__ __forceinline__ float b2f(u16 h){ return __uint_as_float(((u32)h) << 16); }
__device__ __forceinline__ u16   f2b(float f){
  u32 u = __float_as_uint(f);
  u32 r = u + 0x7FFFu + ((u >> 16) & 1u);   // round-to-nearest-even
  return (u16)(r >> 16);
}
__device__ __forceinline__ float lo16(u32 w){ return b2f((u16)(w & 0xFFFFu)); }
__device__ __forceinline__ float hi16(u32 w){ return b2f((u16)(w >> 16)); }

// ---------------- CSR build (by dst); self-loops appended after real edges ----
__global__ void r13_zero(int* p, int n){
  int t = blockIdx.x*blockDim.x + threadIdx.x;
  if (t < n) p[t] = 0;
}

__global__ void r13_hist(const int* ei, int E, int Ep, int* cnt){
  int t = blockIdx.x*blockDim.x + threadIdx.x;
  if (t >= Ep) return;
  int dst = (t < E) ? ei[E + t] : (t - E);
  atomicAdd(&cnt[dst], 1);
}

__global__ void r13_scan1(const int* in, int n, int* incl, int* bsums){
  __shared__ int tmp[256];
  int t = threadIdx.x; int g = blockIdx.x*256 + t;
  int v = (g < n) ? in[g] : 0;
  tmp[t] = v; __syncthreads();
  for (int off = 1; off < 256; off <<= 1){
    int u = (t >= off) ? tmp[t - off] : 0;
    __syncthreads();
    tmp[t] += u;
    __syncthreads();
  }
  if (g < n) incl[g] = tmp[t];
  if (t == 255) bsums[blockIdx.x] = tmp[255];
}

__global__ void r13_scan2(int* bsums, int nb){
  __shared__ int tmp[256];
  int t = threadIdx.x;
  int v = (t < nb) ? bsums[t] : 0;
  tmp[t] = v; __syncthreads();
  for (int off = 1; off < 256; off <<= 1){
    int u = (t >= off) ? tmp[t - off] : 0;
    __syncthreads();
    tmp[t] += u;
    __syncthreads();
  }
  if (t < nb) bsums[t] = tmp[t];
}

__global__ void r13_scan3(const int* incl, const int* cnt, const int* bsums,
                          int n, int Nnodes, int* offs, int* cursor){
  int t = threadIdx.x; int b = blockIdx.x; int g = b*256 + t;
  if (g >= n) return;
  int add = (b > 0) ? bsums[b-1] : 0;
  int ex = incl[g] - cnt[g] + add;       // exclusive prefix
  offs[g] = ex;
  if (g < Nnodes) cursor[g] = ex;
}

__global__ void r13_fill(const int* ei, int E, int Ep, int* cursor, int* csr_src){
  int t = blockIdx.x*blockDim.x + threadIdx.x;
  if (t >= Ep) return;
  int src, dst;
  if (t < E){ src = ei[t]; dst = ei[E + t]; } else { src = t - E; dst = t - E; }
  int pos = atomicAdd(&cursor[dst], 1);
  csr_src[pos] = src;
}

// ---- GEMM: H[n x 128] = X[n x 128] @ W[128 x 128], f32 in, f32 + bf16 out ----
// 64-row x 128-col tile / 256-thread block; each thread 8 rows x 4 cols = 32
// independent FMA chains (fixes r12's ILP=2 latency bind). X staged in LDS
// (32 KB, broadcast reads); W streamed from L1/L2 (float4 per lane).
__global__ __launch_bounds__(256)
void r13_gemm(const float* __restrict__ X, const float* __restrict__ W,
              float* __restrict__ H32, u16* __restrict__ HB, int nrows){
  __shared__ float xs[64*128];   // 32 KB
  int t = threadIdx.x;
  int r0 = blockIdx.x * 64;
  #pragma unroll
  for (int it = 0; it < 8; ++it){
    int idx = it*256 + t;        // float4 index; 32 per 128-elem row
    int row = idx >> 5;
    int c4  = (idx & 31) * 4;
    float4 v = {0.f,0.f,0.f,0.f};
    if (r0 + row < nrows) v = *(const float4*)(X + (size_t)(r0+row)*128 + c4);
    *(float4*)&xs[row*128 + c4] = v;
  }
  __syncthreads();

  int cgrp = t & 31, rgrp = t >> 5;
  int col0 = cgrp * 4;
  float acc[8][4];
  #pragma unroll
  for (int r = 0; r < 8; ++r){
    #pragma unroll
    for (int j = 0; j < 4; ++j) acc[r][j] = 0.f;
  }
  for (int k = 0; k < 128; k += 4){
    float4 xr[8];                              // ds_read_b128 x8 (broadcast in cohort)
    #pragma unroll
    for (int r = 0; r < 8; ++r) xr[r] = *(const float4*)&xs[(rgrp*8 + r)*128 + k];
    #pragma unroll
    for (int kk = 0; kk < 4; ++kk){
      float4 w = *(const float4*)(W + (size_t)(k + kk)*128 + col0);
      #pragma unroll
      for (int r = 0; r < 8; ++r){
        float xv = (&xr[r].x)[kk];
        acc[r][0] = fmaf(xv, w.x, acc[r][0]);
        acc[r][1] = fmaf(xv, w.y, acc[r][1]);
        acc[r][2] = fmaf(xv, w.z, acc[r][2]);
        acc[r][3] = fmaf(xv, w.w, acc[r][3]);
      }
    }
  }
  #pragma unroll
  for (int r = 0; r < 8; ++r){
    int row = r0 + rgrp*8 + r;
    if (row < nrows){
      float4 o = {acc[r][0], acc[r][1], acc[r][2], acc[r][3]};
      *(float4*)(H32 + (size_t)row*128 + col0) = o;
      uint2 pb;
      pb.x = (u32)f2b(acc[r][0]) | ((u32)f2b(acc[r][1]) << 16);
      pb.y = (u32)f2b(acc[r][2]) | ((u32)f2b(acc[r][3]) << 16);
      *(uint2*)&HB[(size_t)row*128 + col0] = pb;
    }
  }
}

// ---- per-node attention dots from f32 h (exact logits) ----
__global__ void r13_dots(const float* __restrict__ H, const float* __restrict__ atts,
                         const float* __restrict__ attd,
                         float* __restrict__ AS, float* __restrict__ AD, int n){
  int wid  = (blockIdx.x*256 + threadIdx.x) >> 6;
  int lane = threadIdx.x & 63;
  if (wid >= n) return;
  float2 hv = ((const float2*)(H + (size_t)wid*128))[lane];
  float2 sv = ((const float2*)atts)[lane];
  float2 dv = ((const float2*)attd)[lane];
  float ps = hv.x*sv.x + hv.y*sv.y;
  float pd = hv.x*dv.x + hv.y*dv.y;
  for (int off = 32; off >= 1; off >>= 1){
    ps += __shfl_xor(ps, off);
    pd += __shfl_xor(pd, off);
  }
  if (lane == 0){ AS[wid] = ps; AD[wid] = pd; }
}

// ---- segment softmax + weighted aggregation; gathers bf16 h (half traffic) ----
__global__ void r13_aggregate(const u16* __restrict__ HB, const float* __restrict__ AS,
                              const float* __restrict__ AD,
                              const int* __restrict__ offs, const int* __restrict__ csr,
                              const float* __restrict__ bias,
                              const float* __restrict__ gamma_, const float* __restrict__ beta_,
                              const float* __restrict__ mean_, const float* __restrict__ var_,
                              float* __restrict__ outp, int n, int doBN){
  int wid  = (blockIdx.x*256 + threadIdx.x) >> 6;
  int lane = threadIdx.x & 63;
  if (wid >= n) return;
  int beg = offs[wid], end = offs[wid+1];
  float ad = AD[wid];
  // pass 1: segment max (stable softmax, matches reference)
  float m = -3.0e38f;
  for (int k = beg + lane; k < end; k += 64){
    int s = csr[k];
    float e = AS[s] + ad; e = (e > 0.f) ? e : 0.2f*e;
    m = fmaxf(m, e);
  }
  for (int off = 32; off >= 1; off >>= 1) m = fmaxf(m, __shfl_xor(m, off));
  // pass 2: denominator
  float den = 0.f;
  for (int k = beg + lane; k < end; k += 64){
    int s = csr[k];
    float e = AS[s] + ad; e = (e > 0.f) ? e : 0.2f*e;
    den += __expf(e - m);
  }
  for (int off = 32; off >= 1; off >>= 1) den += __shfl_xor(den, off);
  float inv = 1.0f / (den + 1e-16f);
  // pass 3: wave walks edges; each lane owns 2 channels; 256 B/edge gather
  float a0 = 0.f, a1 = 0.f;
  for (int k = beg; k < end; ++k){
    int s = csr[k];                                    // wave-uniform
    float e = AS[s] + ad; e = (e > 0.f) ? e : 0.2f*e;
    float al = __expf(e - m) * inv;
    u32 hv = *(const u32*)&HB[(size_t)s*128 + lane*2];
    a0 = fmaf(al, lo16(hv), a0);
    a1 = fmaf(al, hi16(hv), a1);
  }
  int c0 = lane*2;
  float v0 = a0 + bias[c0];
  float v1 = a1 + bias[c0+1];
  v0 = fmaxf(v0, 0.f); v1 = fmaxf(v1, 0.f);            // relu
  if (doBN){
    float s0 = gamma_[c0]   * rsqrtf(var_[c0]   + 1e-5f);
    float s1 = gamma_[c0+1] * rsqrtf(var_[c0+1] + 1e-5f);
    v0 = (v0 - mean_[c0])*s0   + beta_[c0];
    v1 = (v1 - mean_[c0+1])*s1 + beta_[c0+1];
  }
  float2 o = {v0, v1};
  ((float2*)(outp + (size_t)wid*128))[lane] = o;
}

extern "C" void kernel_launch(void* const* d_in, const int* in_sizes, int n_in,
                              void* d_out, int out_size, void* d_ws, size_t ws_size,
                              hipStream_t stream){
  const float* x   = (const float*)d_in[0];
  const int*   ei  = (const int*)  d_in[1];
  const float* W1  = (const float*)d_in[2];
  const float* as1 = (const float*)d_in[3];
  const float* ad1 = (const float*)d_in[4];
  const float* b1  = (const float*)d_in[5];
  const float* bng = (const float*)d_in[6];
  const float* bnb = (const float*)d_in[7];
  const float* bnm = (const float*)d_in[8];
  const float* bnv = (const float*)d_in[9];
  const float* W2  = (const float*)d_in[10];
  const float* as2 = (const float*)d_in[11];
  const float* ad2 = (const float*)d_in[12];
  const float* b2  = (const float*)d_in[13];
  float* out = (float*)d_out;

  int N  = in_sizes[0] / 128;
  int E  = in_sizes[1] / 2;
  int Ep = E + N;
  if (N <= 0 || E <= 0) return;

  // workspace (~58 MB of 256 MB), 256 B-aligned blocks
  char* base = (char*)d_ws;
  size_t off = 0;
  auto alloc = [&](size_t bytes)->char*{
    off = (off + 255) & ~(size_t)255;
    char* q = base + off; off += bytes; return q;
  };
  float* AS     = (float*)alloc((size_t)N*4);
  float* AD     = (float*)alloc((size_t)N*4);
  int*   cnt    = (int*)  alloc((size_t)(N+1)*4);
  int*   offs   = (int*)  alloc((size_t)(N+1)*4);
  int*   cursor = (int*)  alloc((size_t)N*4);
  int*   bsums  = (int*)  alloc(1024);
  int*   csr    = (int*)  alloc((size_t)Ep*4);
  float* h32    = (float*)alloc((size_t)N*128*4);   // 25.6 MB (dots reads f32)
  u16*   hb     = (u16*)  alloc((size_t)N*128*2);   // 12.8 MB (gather reads bf16)
  float* x2     = (float*)alloc((size_t)N*128*4);   // 25.6 MB

  int n1 = N + 1;
  int zb = (n1 + 255)/256;
  int eb = (Ep + 255)/256;
  int sb = (n1 + 255)/256;

  // CSR by dst
  r13_zero <<<zb, 256, 0, stream>>>(cnt, n1);
  r13_hist <<<eb, 256, 0, stream>>>(ei, E, Ep, cnt);
  r13_scan1<<<sb, 256, 0, stream>>>(cnt, n1, offs, bsums);
  r13_scan2<<<1, 256, 0, stream>>>(bsums, sb);
  r13_scan3<<<sb, 256, 0, stream>>>(offs, cnt, bsums, n1, N, offs, cursor);
  r13_fill <<<eb, 256, 0, stream>>>(ei, E, Ep, cursor, csr);

  int gb = (N + 63)/64;   // gemm: 64 rows / block
  int wb = (N + 3)/4;     // wave-per-node kernels: 4 waves / block

  // layer 1: GAT(hid->hid) -> relu -> BN (fused epilogue) -> x2
  r13_gemm     <<<gb, 256, 0, stream>>>(x, W1, h32, hb, N);
  r13_dots     <<<wb, 256, 0, stream>>>(h32, as1, ad1, AS, AD, N);
  r13_aggregate<<<wb, 256, 0, stream>>>(hb, AS, AD, offs, csr, b1, bng, bnb, bnm, bnv,
                                        x2, N, 1);
  // layer 2: GAT(hid->feat) -> relu -> f32 out
  r13_gemm     <<<gb, 256, 0, stream>>>(x2, W2, h32, hb, N);
  r13_dots     <<<wb, 256, 0, stream>>>(h32, as2, ad2, AS, AD, N);
  r13_aggregate<<<wb, 256, 0, stream>>>(hb, AS, AD, offs, csr, b2, 0, 0, 0, 0,
                                        out, N, 0);
}

// Round 14
// 333.703 us; speedup vs baseline: 2.3337x; 1.4036x over previous
//
// rev r14 — aggregate: single-pass register softmax (deg<=64 fast path) +
// 4-way-unrolled shfl-broadcast gather (4 outstanding loads). gemm: dots fused
// into epilogue (AS/AD via cohort shuffle reduce), f32 H dropped (bf16 HB only),
// k-loop unroll 2. r13: 468 µs (aggregate 2x103, latency-bound serial gather).
#include <hip/hip_runtime.h>

typedef unsigned short u16;
typedef unsigned int   u32;

__device__ __forceinline__ float b2f(u16 h){ return __uint_as_float(((u32)h) << 16); }
__device__ __forceinline__ u16   f2b(float f){
  u32 u = __float_as_uint(f);
  u32 r = u + 0x7FFFu + ((u >> 16) & 1u);   // round-to-nearest-even
  return (u16)(r >> 16);
}
__device__ __forceinline__ float lo16(u32 w){ return b2f((u16)(w & 0xFFFFu)); }
__device__ __forceinline__ float hi16(u32 w){ return b2f((u16)(w >> 16)); }

// ---------------- CSR build (by dst); self-loops appended after real edges ----
__global__ void r14_zero(int* p, int n){
  int t = blockIdx.x*blockDim.x + threadIdx.x;
  if (t < n) p[t] = 0;
}

__global__ void r14_hist(const int* ei, int E, int Ep, int* cnt){
  int t = blockIdx.x*blockDim.x + threadIdx.x;
  if (t >= Ep) return;
  int dst = (t < E) ? ei[E + t] : (t - E);
  atomicAdd(&cnt[dst], 1);
}

__global__ void r14_scan1(const int* in, int n, int* incl, int* bsums){
  __shared__ int tmp[256];
  int t = threadIdx.x; int g = blockIdx.x*256 + t;
  int v = (g < n) ? in[g] : 0;
  tmp[t] = v; __syncthreads();
  for (int off = 1; off < 256; off <<= 1){
    int u = (t >= off) ? tmp[t - off] : 0;
    __syncthreads();
    tmp[t] += u;
    __syncthreads();
  }
  if (g < n) incl[g] = tmp[t];
  if (t == 255) bsums[blockIdx.x] = tmp[255];
}

__global__ void r14_scan2(int* bsums, int nb){
  __shared__ int tmp[256];
  int t = threadIdx.x;
  int v = (t < nb) ? bsums[t] : 0;
  tmp[t] = v; __syncthreads();
  for (int off = 1; off < 256; off <<= 1){
    int u = (t >= off) ? tmp[t - off] : 0;
    __syncthreads();
    tmp[t] += u;
    __syncthreads();
  }
  if (t < nb) bsums[t] = tmp[t];
}

__global__ void r14_scan3(const int* incl, const int* cnt, const int* bsums,
                          int n, int Nnodes, int* offs, int* cursor){
  int t = threadIdx.x; int b = blockIdx.x; int g = b*256 + t;
  if (g >= n) return;
  int add = (b > 0) ? bsums[b-1] : 0;
  int ex = incl[g] - cnt[g] + add;       // exclusive prefix
  offs[g] = ex;
  if (g < Nnodes) cursor[g] = ex;
}

__global__ void r14_fill(const int* ei, int E, int Ep, int* cursor, int* csr_src){
  int t = blockIdx.x*blockDim.x + threadIdx.x;
  if (t >= Ep) return;
  int src, dst;
  if (t < E){ src = ei[t]; dst = ei[E + t]; } else { src = t - E; dst = t - E; }
  int pos = atomicAdd(&cursor[dst], 1);
  csr_src[pos] = src;
}

// ---- fused GEMM + attention dots ----
// H = X @ W (f32 acc), stored bf16 (gather operand). AS/AD = H·att_src/dst
// computed from f32 acc in epilogue via cohort shuffle reduce (exact logits).
// 64-row x 128-col tile / 256 threads; thread owns 8 rows x 4 cols.
__global__ __launch_bounds__(256)
void r14_gemm(const float* __restrict__ X, const float* __restrict__ W,
              const float* __restrict__ atts, const float* __restrict__ attd,
              u16* __restrict__ HB, float* __restrict__ AS, float* __restrict__ AD,
              int nrows){
  __shared__ float xs[64*128];   // 32 KB
  int t = threadIdx.x;
  int r0 = blockIdx.x * 64;
  #pragma unroll
  for (int it = 0; it < 8; ++it){
    int idx = it*256 + t;        // float4 index; 32 per 128-elem row
    int row = idx >> 5;
    int c4  = (idx & 31) * 4;
    float4 v = {0.f,0.f,0.f,0.f};
    if (r0 + row < nrows) v = *(const float4*)(X + (size_t)(r0+row)*128 + c4);
    *(float4*)&xs[row*128 + c4] = v;
  }
  __syncthreads();

  int cgrp = t & 31, rgrp = t >> 5;
  int col0 = cgrp * 4;
  float acc[8][4];
  #pragma unroll
  for (int r = 0; r < 8; ++r){
    #pragma unroll
    for (int j = 0; j < 4; ++j) acc[r][j] = 0.f;
  }
  #pragma unroll 2
  for (int k = 0; k < 128; k += 4){
    float4 w0 = *(const float4*)(W + (size_t)(k+0)*128 + col0);
    float4 w1 = *(const float4*)(W + (size_t)(k+1)*128 + col0);
    float4 w2 = *(const float4*)(W + (size_t)(k+2)*128 + col0);
    float4 w3 = *(const float4*)(W + (size_t)(k+3)*128 + col0);
    float4 xr[8];
    #pragma unroll
    for (int r = 0; r < 8; ++r) xr[r] = *(const float4*)&xs[(rgrp*8 + r)*128 + k];
    #pragma unroll
    for (int r = 0; r < 8; ++r){
      acc[r][0] = fmaf(xr[r].x, w0.x, acc[r][0]);
      acc[r][1] = fmaf(xr[r].x, w0.y, acc[r][1]);
      acc[r][2] = fmaf(xr[r].x, w0.z, acc[r][2]);
      acc[r][3] = fmaf(xr[r].x, w0.w, acc[r][3]);
      acc[r][0] = fmaf(xr[r].y, w1.x, acc[r][0]);
      acc[r][1] = fmaf(xr[r].y, w1.y, acc[r][1]);
      acc[r][2] = fmaf(xr[r].y, w1.z, acc[r][2]);
      acc[r][3] = fmaf(xr[r].y, w1.w, acc[r][3]);
      acc[r][0] = fmaf(xr[r].z, w2.x, acc[r][0]);
      acc[r][1] = fmaf(xr[r].z, w2.y, acc[r][1]);
      acc[r][2] = fmaf(xr[r].z, w2.z, acc[r][2]);
      acc[r][3] = fmaf(xr[r].z, w2.w, acc[r][3]);
      acc[r][0] = fmaf(xr[r].w, w3.x, acc[r][0]);
      acc[r][1] = fmaf(xr[r].w, w3.y, acc[r][1]);
      acc[r][2] = fmaf(xr[r].w, w3.z, acc[r][2]);
      acc[r][3] = fmaf(xr[r].w, w3.w, acc[r][3]);
    }
  }
  // epilogue: bf16 store + fused dots (reduce across the 32-lane col cohort)
  float4 sv = *(const float4*)(atts + col0);
  float4 dv = *(const float4*)(attd + col0);
  #pragma unroll
  for (int r = 0; r < 8; ++r){
    int row = r0 + rgrp*8 + r;
    float ps = acc[r][0]*sv.x + acc[r][1]*sv.y + acc[r][2]*sv.z + acc[r][3]*sv.w;
    float pd = acc[r][0]*dv.x + acc[r][1]*dv.y + acc[r][2]*dv.z + acc[r][3]*dv.w;
    #pragma unroll
    for (int off = 16; off >= 1; off >>= 1){  // xor<32 stays in 32-lane half
      ps += __shfl_xor(ps, off);
      pd += __shfl_xor(pd, off);
    }
    if (row < nrows){
      uint2 pb;
      pb.x = (u32)f2b(acc[r][0]) | ((u32)f2b(acc[r][1]) << 16);
      pb.y = (u32)f2b(acc[r][2]) | ((u32)f2b(acc[r][3]) << 16);
      *(uint2*)&HB[(size_t)row*128 + col0] = pb;
      if (cgrp == 0){ AS[row] = ps; AD[row] = pd; }
    }
  }
}

// ---- segment softmax + aggregation (one wave / dst node) ----
// deg<=64 fast path: (src,e) loaded once per edge into registers; m/denom via
// shuffle reduce; serial gather unrolled x4 with shfl-broadcast (4 loads in
// flight). Generic 3-pass fallback for deg>64 (prob ~0 at Poisson(17)).
__global__ __launch_bounds__(256)
void r14_aggregate(const u16* __restrict__ HB, const float* __restrict__ AS,
                   const float* __restrict__ AD,
                   const int* __restrict__ offs, const int* __restrict__ csr,
                   const float* __restrict__ bias,
                   const float* __restrict__ gamma_, const float* __restrict__ beta_,
                   const float* __restrict__ mean_, const float* __restrict__ var_,
                   float* __restrict__ outp, int n, int doBN){
  int wid  = (blockIdx.x*256 + threadIdx.x) >> 6;
  int lane = threadIdx.x & 63;
  if (wid >= n) return;
  int beg = offs[wid], end = offs[wid+1];
  int deg = end - beg;
  float ad = AD[wid];
  int c2 = lane*2;
  float a0 = 0.f, a1 = 0.f;

  if (deg <= 64){
    int   my_s = 0;
    float my_e = -3.0e38f;
    int myk = beg + lane;
    bool act = (myk < end);
    if (act){
      my_s = csr[myk];
      float e = AS[my_s] + ad;
      my_e = (e > 0.f) ? e : 0.2f*e;
    }
    float m = my_e;
    #pragma unroll
    for (int off = 32; off >= 1; off >>= 1) m = fmaxf(m, __shfl_xor(m, off));
    float pz = act ? __expf(my_e - m) : 0.f;
    float den = pz;
    #pragma unroll
    for (int off = 32; off >= 1; off >>= 1) den += __shfl_xor(den, off);
    float my_al = pz / (den + 1e-16f);

    int j = 0;
    for (; j + 4 <= deg; j += 4){
      int   s0 = __shfl(my_s, j),   s1 = __shfl(my_s, j+1);
      int   s2 = __shfl(my_s, j+2), s3 = __shfl(my_s, j+3);
      float l0 = __shfl(my_al, j),   l1 = __shfl(my_al, j+1);
      float l2 = __shfl(my_al, j+2), l3 = __shfl(my_al, j+3);
      u32 h0 = *(const u32*)&HB[(size_t)s0*128 + c2];
      u32 h1 = *(const u32*)&HB[(size_t)s1*128 + c2];
      u32 h2 = *(const u32*)&HB[(size_t)s2*128 + c2];
      u32 h3 = *(const u32*)&HB[(size_t)s3*128 + c2];
      a0 = fmaf(l0, lo16(h0), a0); a1 = fmaf(l0, hi16(h0), a1);
      a0 = fmaf(l1, lo16(h1), a0); a1 = fmaf(l1, hi16(h1), a1);
      a0 = fmaf(l2, lo16(h2), a0); a1 = fmaf(l2, hi16(h2), a1);
      a0 = fmaf(l3, lo16(h3), a0); a1 = fmaf(l3, hi16(h3), a1);
    }
    for (; j < deg; ++j){
      int   s = __shfl(my_s, j);
      float l = __shfl(my_al, j);
      u32 hv = *(const u32*)&HB[(size_t)s*128 + c2];
      a0 = fmaf(l, lo16(hv), a0); a1 = fmaf(l, hi16(hv), a1);
    }
  } else {
    // generic 3-pass path (identical math to r13)
    float m = -3.0e38f;
    for (int k = beg + lane; k < end; k += 64){
      int s = csr[k];
      float e = AS[s] + ad; e = (e > 0.f) ? e : 0.2f*e;
      m = fmaxf(m, e);
    }
    #pragma unroll
    for (int off = 32; off >= 1; off >>= 1) m = fmaxf(m, __shfl_xor(m, off));
    float den = 0.f;
    for (int k = beg + lane; k < end; k += 64){
      int s = csr[k];
      float e = AS[s] + ad; e = (e > 0.f) ? e : 0.2f*e;
      den += __expf(e - m);
    }
    #pragma unroll
    for (int off = 32; off >= 1; off >>= 1) den += __shfl_xor(den, off);
    float inv = 1.0f / (den + 1e-16f);
    for (int k = beg; k < end; ++k){
      int s = csr[k];
      float e = AS[s] + ad; e = (e > 0.f) ? e : 0.2f*e;
      float al = __expf(e - m) * inv;
      u32 hv = *(const u32*)&HB[(size_t)s*128 + c2];
      a0 = fmaf(al, lo16(hv), a0); a1 = fmaf(al, hi16(hv), a1);
    }
  }

  float v0 = a0 + bias[c2];
  float v1 = a1 + bias[c2+1];
  v0 = fmaxf(v0, 0.f); v1 = fmaxf(v1, 0.f);            // relu
  if (doBN){
    float s0 = gamma_[c2]   * rsqrtf(var_[c2]   + 1e-5f);
    float s1 = gamma_[c2+1] * rsqrtf(var_[c2+1] + 1e-5f);
    v0 = (v0 - mean_[c2])*s0   + beta_[c2];
    v1 = (v1 - mean_[c2+1])*s1 + beta_[c2+1];
  }
  float2 o = {v0, v1};
  ((float2*)(outp + (size_t)wid*128))[lane] = o;
}

extern "C" void kernel_launch(void* const* d_in, const int* in_sizes, int n_in,
                              void* d_out, int out_size, void* d_ws, size_t ws_size,
                              hipStream_t stream){
  const float* x   = (const float*)d_in[0];
  const int*   ei  = (const int*)  d_in[1];
  const float* W1  = (const float*)d_in[2];
  const float* as1 = (const float*)d_in[3];
  const float* ad1 = (const float*)d_in[4];
  const float* b1  = (const float*)d_in[5];
  const float* bng = (const float*)d_in[6];
  const float* bnb = (const float*)d_in[7];
  const float* bnm = (const float*)d_in[8];
  const float* bnv = (const float*)d_in[9];
  const float* W2  = (const float*)d_in[10];
  const float* as2 = (const float*)d_in[11];
  const float* ad2 = (const float*)d_in[12];
  const float* b2  = (const float*)d_in[13];
  float* out = (float*)d_out;

  int N  = in_sizes[0] / 128;
  int E  = in_sizes[1] / 2;
  int Ep = E + N;
  if (N <= 0 || E <= 0) return;

  // workspace (~43 MB of 256 MB), 256 B-aligned
  char* base = (char*)d_ws;
  size_t off = 0;
  auto alloc = [&](size_t bytes)->char*{
    off = (off + 255) & ~(size_t)255;
    char* q = base + off; off += bytes; return q;
  };
  float* AS     = (float*)alloc((size_t)N*4);
  float* AD     = (float*)alloc((size_t)N*4);
  int*   cnt    = (int*)  alloc((size_t)(N+1)*4);
  int*   offs   = (int*)  alloc((size_t)(N+1)*4);
  int*   cursor = (int*)  alloc((size_t)N*4);
  int*   bsums  = (int*)  alloc(1024);
  int*   csr    = (int*)  alloc((size_t)Ep*4);
  u16*   hb     = (u16*)  alloc((size_t)N*128*2);   // 12.8 MB bf16 gather operand
  float* x2     = (float*)alloc((size_t)N*128*4);   // 25.6 MB

  int n1 = N + 1;
  int zb = (n1 + 255)/256;
  int eb = (Ep + 255)/256;
  int sb = (n1 + 255)/256;

  // CSR by dst
  r14_zero <<<zb, 256, 0, stream>>>(cnt, n1);
  r14_hist <<<eb, 256, 0, stream>>>(ei, E, Ep, cnt);
  r14_scan1<<<sb, 256, 0, stream>>>(cnt, n1, offs, bsums);
  r14_scan2<<<1, 256, 0, stream>>>(bsums, sb);
  r14_scan3<<<sb, 256, 0, stream>>>(offs, cnt, bsums, n1, N, offs, cursor);
  r14_fill <<<eb, 256, 0, stream>>>(ei, E, Ep, cursor, csr);

  int gb = (N + 63)/64;   // gemm: 64 rows / block
  int wb = (N + 3)/4;     // aggregate: 4 waves / block

  // layer 1: GAT(hid->hid) -> relu -> BN (fused epilogue) -> x2
  r14_gemm     <<<gb, 256, 0, stream>>>(x, W1, as1, ad1, hb, AS, AD, N);
  r14_aggregate<<<wb, 256, 0, stream>>>(hb, AS, AD, offs, csr, b1, bng, bnb, bnm, bnv,
                                        x2, N, 1);
  // layer 2: GAT(hid->feat) -> relu -> f32 out
  r14_gemm     <<<gb, 256, 0, stream>>>(x2, W2, as2, ad2, hb, AS, AD, N);
  r14_aggregate<<<wb, 256, 0, stream>>>(hb, AS, AD, offs, csr, b2, 0, 0, 0, 0,
                                        out, N, 0);
}

// Round 15
// 298.352 us; speedup vs baseline: 2.6103x; 1.1185x over previous
//
// rev r15 — hide the CSR fill (56 µs, 16x write-amplified scatter, VALU 0.5%)
// behind layer-1 GEMM (VALU-bound) via a fat kernel with block-role switch.
// aggregate gather unroll 4 -> 8. r14: 334 µs, absmax 3.9e-3.
#include <hip/hip_runtime.h>

typedef unsigned short u16;
typedef unsigned int   u32;

__device__ __forceinline__ float b2f(u16 h){ return __uint_as_float(((u32)h) << 16); }
__device__ __forceinline__ u16   f2b(float f){
  u32 u = __float_as_uint(f);
  u32 r = u + 0x7FFFu + ((u >> 16) & 1u);   // round-to-nearest-even
  return (u16)(r >> 16);
}
__device__ __forceinline__ float lo16(u32 w){ return b2f((u16)(w & 0xFFFFu)); }
__device__ __forceinline__ float hi16(u32 w){ return b2f((u16)(w >> 16)); }

// ---------------- CSR build (by dst); self-loops appended after real edges ----
__global__ void r15_zero(int* p, int n){
  int t = blockIdx.x*blockDim.x + threadIdx.x;
  if (t < n) p[t] = 0;
}

__global__ void r15_hist(const int* ei, int E, int Ep, int* cnt){
  int t = blockIdx.x*blockDim.x + threadIdx.x;
  if (t >= Ep) return;
  int dst = (t < E) ? ei[E + t] : (t - E);
  atomicAdd(&cnt[dst], 1);
}

__global__ void r15_scan1(const int* in, int n, int* incl, int* bsums){
  __shared__ int tmp[256];
  int t = threadIdx.x; int g = blockIdx.x*256 + t;
  int v = (g < n) ? in[g] : 0;
  tmp[t] = v; __syncthreads();
  for (int off = 1; off < 256; off <<= 1){
    int u = (t >= off) ? tmp[t - off] : 0;
    __syncthreads();
    tmp[t] += u;
    __syncthreads();
  }
  if (g < n) incl[g] = tmp[t];
  if (t == 255) bsums[blockIdx.x] = tmp[255];
}

__global__ void r15_scan2(int* bsums, int nb){
  __shared__ int tmp[256];
  int t = threadIdx.x;
  int v = (t < nb) ? bsums[t] : 0;
  tmp[t] = v; __syncthreads();
  for (int off = 1; off < 256; off <<= 1){
    int u = (t >= off) ? tmp[t - off] : 0;
    __syncthreads();
    tmp[t] += u;
    __syncthreads();
  }
  if (t < nb) bsums[t] = tmp[t];
}

__global__ void r15_scan3(const int* incl, const int* cnt, const int* bsums,
                          int n, int Nnodes, int* offs, int* cursor){
  int t = threadIdx.x; int b = blockIdx.x; int g = b*256 + t;
  if (g >= n) return;
  int add = (b > 0) ? bsums[b-1] : 0;
  int ex = incl[g] - cnt[g] + add;       // exclusive prefix
  offs[g] = ex;
  if (g < Nnodes) cursor[g] = ex;
}

// ---- FAT kernel: blocks [0,gemmBlocks) = fused GEMM+dots; rest = CSR fill ----
// GEMM: H = X @ W (f32 acc) -> bf16 HB; AS/AD fused in epilogue (f32-exact).
// Fill: scatter edges into csr (memory-bound, VALU 0.5%) — co-scheduled with
// the VALU-bound GEMM so its ~56 µs hides (m114: concurrent pipes, time≈max).
__global__ __launch_bounds__(256)
void r15_gemm_fill(const float* __restrict__ X, const float* __restrict__ W,
                   const float* __restrict__ atts, const float* __restrict__ attd,
                   u16* __restrict__ HB, float* __restrict__ AS, float* __restrict__ AD,
                   int nrows, int gemmBlocks,
                   const int* __restrict__ ei, int E, int Ep,
                   int* cursor, int* csr_src){
  __shared__ float xs[64*128];   // 32 KB (fill blocks don't touch it)
  int t = threadIdx.x;

  if ((int)blockIdx.x >= gemmBlocks){
    // ---------------- fill role ----------------
    int g = ((int)blockIdx.x - gemmBlocks)*256 + t;
    if (g < Ep){
      int src, dst;
      if (g < E){ src = ei[g]; dst = ei[E + g]; } else { src = g - E; dst = g - E; }
      int pos = atomicAdd(&cursor[dst], 1);
      csr_src[pos] = src;
    }
    return;
  }

  // ---------------- gemm role ----------------
  int r0 = blockIdx.x * 64;
  #pragma unroll
  for (int it = 0; it < 8; ++it){
    int idx = it*256 + t;        // float4 index; 32 per 128-elem row
    int row = idx >> 5;
    int c4  = (idx & 31) * 4;
    float4 v = {0.f,0.f,0.f,0.f};
    if (r0 + row < nrows) v = *(const float4*)(X + (size_t)(r0+row)*128 + c4);
    *(float4*)&xs[row*128 + c4] = v;
  }
  __syncthreads();

  int cgrp = t & 31, rgrp = t >> 5;
  int col0 = cgrp * 4;
  float acc[8][4];
  #pragma unroll
  for (int r = 0; r < 8; ++r){
    #pragma unroll
    for (int j = 0; j < 4; ++j) acc[r][j] = 0.f;
  }
  #pragma unroll 2
  for (int k = 0; k < 128; k += 4){
    float4 w0 = *(const float4*)(W + (size_t)(k+0)*128 + col0);
    float4 w1 = *(const float4*)(W + (size_t)(k+1)*128 + col0);
    float4 w2 = *(const float4*)(W + (size_t)(k+2)*128 + col0);
    float4 w3 = *(const float4*)(W + (size_t)(k+3)*128 + col0);
    float4 xr[8];
    #pragma unroll
    for (int r = 0; r < 8; ++r) xr[r] = *(const float4*)&xs[(rgrp*8 + r)*128 + k];
    #pragma unroll
    for (int r = 0; r < 8; ++r){
      acc[r][0] = fmaf(xr[r].x, w0.x, acc[r][0]);
      acc[r][1] = fmaf(xr[r].x, w0.y, acc[r][1]);
      acc[r][2] = fmaf(xr[r].x, w0.z, acc[r][2]);
      acc[r][3] = fmaf(xr[r].x, w0.w, acc[r][3]);
      acc[r][0] = fmaf(xr[r].y, w1.x, acc[r][0]);
      acc[r][1] = fmaf(xr[r].y, w1.y, acc[r][1]);
      acc[r][2] = fmaf(xr[r].y, w1.z, acc[r][2]);
      acc[r][3] = fmaf(xr[r].y, w1.w, acc[r][3]);
      acc[r][0] = fmaf(xr[r].z, w2.x, acc[r][0]);
      acc[r][1] = fmaf(xr[r].z, w2.y, acc[r][1]);
      acc[r][2] = fmaf(xr[r].z, w2.z, acc[r][2]);
      acc[r][3] = fmaf(xr[r].z, w2.w, acc[r][3]);
      acc[r][0] = fmaf(xr[r].w, w3.x, acc[r][0]);
      acc[r][1] = fmaf(xr[r].w, w3.y, acc[r][1]);
      acc[r][2] = fmaf(xr[r].w, w3.z, acc[r][2]);
      acc[r][3] = fmaf(xr[r].w, w3.w, acc[r][3]);
    }
  }
  float4 sv = *(const float4*)(atts + col0);
  float4 dv = *(const float4*)(attd + col0);
  #pragma unroll
  for (int r = 0; r < 8; ++r){
    int row = r0 + rgrp*8 + r;
    float ps = acc[r][0]*sv.x + acc[r][1]*sv.y + acc[r][2]*sv.z + acc[r][3]*sv.w;
    float pd = acc[r][0]*dv.x + acc[r][1]*dv.y + acc[r][2]*dv.z + acc[r][3]*dv.w;
    #pragma unroll
    for (int off = 16; off >= 1; off >>= 1){  // reduce within 32-lane cohort
      ps += __shfl_xor(ps, off);
      pd += __shfl_xor(pd, off);
    }
    if (row < nrows){
      uint2 pb;
      pb.x = (u32)f2b(acc[r][0]) | ((u32)f2b(acc[r][1]) << 16);
      pb.y = (u32)f2b(acc[r][2]) | ((u32)f2b(acc[r][3]) << 16);
      *(uint2*)&HB[(size_t)row*128 + col0] = pb;
      if (cgrp == 0){ AS[row] = ps; AD[row] = pd; }
    }
  }
}

// plain gemm (layer 2 — no fill partner)
__global__ __launch_bounds__(256)
void r15_gemm(const float* __restrict__ X, const float* __restrict__ W,
              const float* __restrict__ atts, const float* __restrict__ attd,
              u16* __restrict__ HB, float* __restrict__ AS, float* __restrict__ AD,
              int nrows){
  __shared__ float xs[64*128];
  int t = threadIdx.x;
  int r0 = blockIdx.x * 64;
  #pragma unroll
  for (int it = 0; it < 8; ++it){
    int idx = it*256 + t;
    int row = idx >> 5;
    int c4  = (idx & 31) * 4;
    float4 v = {0.f,0.f,0.f,0.f};
    if (r0 + row < nrows) v = *(const float4*)(X + (size_t)(r0+row)*128 + c4);
    *(float4*)&xs[row*128 + c4] = v;
  }
  __syncthreads();
  int cgrp = t & 31, rgrp = t >> 5;
  int col0 = cgrp * 4;
  float acc[8][4];
  #pragma unroll
  for (int r = 0; r < 8; ++r){
    #pragma unroll
    for (int j = 0; j < 4; ++j) acc[r][j] = 0.f;
  }
  #pragma unroll 2
  for (int k = 0; k < 128; k += 4){
    float4 w0 = *(const float4*)(W + (size_t)(k+0)*128 + col0);
    float4 w1 = *(const float4*)(W + (size_t)(k+1)*128 + col0);
    float4 w2 = *(const float4*)(W + (size_t)(k+2)*128 + col0);
    float4 w3 = *(const float4*)(W + (size_t)(k+3)*128 + col0);
    float4 xr[8];
    #pragma unroll
    for (int r = 0; r < 8; ++r) xr[r] = *(const float4*)&xs[(rgrp*8 + r)*128 + k];
    #pragma unroll
    for (int r = 0; r < 8; ++r){
      acc[r][0] = fmaf(xr[r].x, w0.x, acc[r][0]);
      acc[r][1] = fmaf(xr[r].x, w0.y, acc[r][1]);
      acc[r][2] = fmaf(xr[r].x, w0.z, acc[r][2]);
      acc[r][3] = fmaf(xr[r].x, w0.w, acc[r][3]);
      acc[r][0] = fmaf(xr[r].y, w1.x, acc[r][0]);
      acc[r][1] = fmaf(xr[r].y, w1.y, acc[r][1]);
      acc[r][2] = fmaf(xr[r].y, w1.z, acc[r][2]);
      acc[r][3] = fmaf(xr[r].y, w1.w, acc[r][3]);
      acc[r][0] = fmaf(xr[r].z, w2.x, acc[r][0]);
      acc[r][1] = fmaf(xr[r].z, w2.y, acc[r][1]);
      acc[r][2] = fmaf(xr[r].z, w2.z, acc[r][2]);
      acc[r][3] = fmaf(xr[r].z, w2.w, acc[r][3]);
      acc[r][0] = fmaf(xr[r].w, w3.x, acc[r][0]);
      acc[r][1] = fmaf(xr[r].w, w3.y, acc[r][1]);
      acc[r][2] = fmaf(xr[r].w, w3.z, acc[r][2]);
      acc[r][3] = fmaf(xr[r].w, w3.w, acc[r][3]);
    }
  }
  float4 sv = *(const float4*)(atts + col0);
  float4 dv = *(const float4*)(attd + col0);
  #pragma unroll
  for (int r = 0; r < 8; ++r){
    int row = r0 + rgrp*8 + r;
    float ps = acc[r][0]*sv.x + acc[r][1]*sv.y + acc[r][2]*sv.z + acc[r][3]*sv.w;
    float pd = acc[r][0]*dv.x + acc[r][1]*dv.y + acc[r][2]*dv.z + acc[r][3]*dv.w;
    #pragma unroll
    for (int off = 16; off >= 1; off >>= 1){
      ps += __shfl_xor(ps, off);
      pd += __shfl_xor(pd, off);
    }
    if (row < nrows){
      uint2 pb;
      pb.x = (u32)f2b(acc[r][0]) | ((u32)f2b(acc[r][1]) << 16);
      pb.y = (u32)f2b(acc[r][2]) | ((u32)f2b(acc[r][3]) << 16);
      *(uint2*)&HB[(size_t)row*128 + col0] = pb;
      if (cgrp == 0){ AS[row] = ps; AD[row] = pd; }
    }
  }
}

// ---- segment softmax + aggregation (one wave / dst node), gather unroll x8 ----
__global__ __launch_bounds__(256)
void r15_aggregate(const u16* __restrict__ HB, const float* __restrict__ AS,
                   const float* __restrict__ AD,
                   const int* __restrict__ offs, const int* __restrict__ csr,
                   const float* __restrict__ bias,
                   const float* __restrict__ gamma_, const float* __restrict__ beta_,
                   const float* __restrict__ mean_, const float* __restrict__ var_,
                   float* __restrict__ outp, int n, int doBN){
  int wid  = (blockIdx.x*256 + threadIdx.x) >> 6;
  int lane = threadIdx.x & 63;
  if (wid >= n) return;
  int beg = offs[wid], end = offs[wid+1];
  int deg = end - beg;
  float ad = AD[wid];
  int c2 = lane*2;
  float a0 = 0.f, a1 = 0.f;

  if (deg <= 64){
    int   my_s = 0;
    float my_e = -3.0e38f;
    int myk = beg + lane;
    bool act = (myk < end);
    if (act){
      my_s = csr[myk];
      float e = AS[my_s] + ad;
      my_e = (e > 0.f) ? e : 0.2f*e;
    }
    float m = my_e;
    #pragma unroll
    for (int off = 32; off >= 1; off >>= 1) m = fmaxf(m, __shfl_xor(m, off));
    float pz = act ? __expf(my_e - m) : 0.f;
    float den = pz;
    #pragma unroll
    for (int off = 32; off >= 1; off >>= 1) den += __shfl_xor(den, off);
    float my_al = pz / (den + 1e-16f);

    int j = 0;
    for (; j + 8 <= deg; j += 8){
      int   s0 = __shfl(my_s, j),   s1 = __shfl(my_s, j+1);
      int   s2 = __shfl(my_s, j+2), s3 = __shfl(my_s, j+3);
      int   s4 = __shfl(my_s, j+4), s5 = __shfl(my_s, j+5);
      int   s6 = __shfl(my_s, j+6), s7 = __shfl(my_s, j+7);
      float l0 = __shfl(my_al, j),   l1 = __shfl(my_al, j+1);
      float l2 = __shfl(my_al, j+2), l3 = __shfl(my_al, j+3);
      float l4 = __shfl(my_al, j+4), l5 = __shfl(my_al, j+5);
      float l6 = __shfl(my_al, j+6), l7 = __shfl(my_al, j+7);
      u32 h0 = *(const u32*)&HB[(size_t)s0*128 + c2];
      u32 h1 = *(const u32*)&HB[(size_t)s1*128 + c2];
      u32 h2 = *(const u32*)&HB[(size_t)s2*128 + c2];
      u32 h3 = *(const u32*)&HB[(size_t)s3*128 + c2];
      u32 h4 = *(const u32*)&HB[(size_t)s4*128 + c2];
      u32 h5 = *(const u32*)&HB[(size_t)s5*128 + c2];
      u32 h6 = *(const u32*)&HB[(size_t)s6*128 + c2];
      u32 h7 = *(const u32*)&HB[(size_t)s7*128 + c2];
      a0 = fmaf(l0, lo16(h0), a0); a1 = fmaf(l0, hi16(h0), a1);
      a0 = fmaf(l1, lo16(h1), a0); a1 = fmaf(l1, hi16(h1), a1);
      a0 = fmaf(l2, lo16(h2), a0); a1 = fmaf(l2, hi16(h2), a1);
      a0 = fmaf(l3, lo16(h3), a0); a1 = fmaf(l3, hi16(h3), a1);
      a0 = fmaf(l4, lo16(h4), a0); a1 = fmaf(l4, hi16(h4), a1);
      a0 = fmaf(l5, lo16(h5), a0); a1 = fmaf(l5, hi16(h5), a1);
      a0 = fmaf(l6, lo16(h6), a0); a1 = fmaf(l6, hi16(h6), a1);
      a0 = fmaf(l7, lo16(h7), a0); a1 = fmaf(l7, hi16(h7), a1);
    }
    for (; j + 4 <= deg; j += 4){
      int   s0 = __shfl(my_s, j),   s1 = __shfl(my_s, j+1);
      int   s2 = __shfl(my_s, j+2), s3 = __shfl(my_s, j+3);
      float l0 = __shfl(my_al, j),   l1 = __shfl(my_al, j+1);
      float l2 = __shfl(my_al, j+2), l3 = __shfl(my_al, j+3);
      u32 h0 = *(const u32*)&HB[(size_t)s0*128 + c2];
      u32 h1 = *(const u32*)&HB[(size_t)s1*128 + c2];
      u32 h2 = *(const u32*)&HB[(size_t)s2*128 + c2];
      u32 h3 = *(const u32*)&HB[(size_t)s3*128 + c2];
      a0 = fmaf(l0, lo16(h0), a0); a1 = fmaf(l0, hi16(h0), a1);
      a0 = fmaf(l1, lo16(h1), a0); a1 = fmaf(l1, hi16(h1), a1);
      a0 = fmaf(l2, lo16(h2), a0); a1 = fmaf(l2, hi16(h2), a1);
      a0 = fmaf(l3, lo16(h3), a0); a1 = fmaf(l3, hi16(h3), a1);
    }
    for (; j < deg; ++j){
      int   s = __shfl(my_s, j);
      float l = __shfl(my_al, j);
      u32 hv = *(const u32*)&HB[(size_t)s*128 + c2];
      a0 = fmaf(l, lo16(hv), a0); a1 = fmaf(l, hi16(hv), a1);
    }
  } else {
    float m = -3.0e38f;
    for (int k = beg + lane; k < end; k += 64){
      int s = csr[k];
      float e = AS[s] + ad; e = (e > 0.f) ? e : 0.2f*e;
      m = fmaxf(m, e);
    }
    #pragma unroll
    for (int off = 32; off >= 1; off >>= 1) m = fmaxf(m, __shfl_xor(m, off));
    float den = 0.f;
    for (int k = beg + lane; k < end; k += 64){
      int s = csr[k];
      float e = AS[s] + ad; e = (e > 0.f) ? e : 0.2f*e;
      den += __expf(e - m);
    }
    #pragma unroll
    for (int off = 32; off >= 1; off >>= 1) den += __shfl_xor(den, off);
    float inv = 1.0f / (den + 1e-16f);
    for (int k = beg; k < end; ++k){
      int s = csr[k];
      float e = AS[s] + ad; e = (e > 0.f) ? e : 0.2f*e;
      float al = __expf(e - m) * inv;
      u32 hv = *(const u32*)&HB[(size_t)s*128 + c2];
      a0 = fmaf(al, lo16(hv), a0); a1 = fmaf(al, hi16(hv), a1);
    }
  }

  float v0 = a0 + bias[c2];
  float v1 = a1 + bias[c2+1];
  v0 = fmaxf(v0, 0.f); v1 = fmaxf(v1, 0.f);            // relu
  if (doBN){
    float s0 = gamma_[c2]   * rsqrtf(var_[c2]   + 1e-5f);
    float s1 = gamma_[c2+1] * rsqrtf(var_[c2+1] + 1e-5f);
    v0 = (v0 - mean_[c2])*s0   + beta_[c2];
    v1 = (v1 - mean_[c2+1])*s1 + beta_[c2+1];
  }
  float2 o = {v0, v1};
  ((float2*)(outp + (size_t)wid*128))[lane] = o;
}

extern "C" void kernel_launch(void* const* d_in, const int* in_sizes, int n_in,
                              void* d_out, int out_size, void* d_ws, size_t ws_size,
                              hipStream_t stream){
  const float* x   = (const float*)d_in[0];
  const int*   ei  = (const int*)  d_in[1];
  const float* W1  = (const float*)d_in[2];
  const float* as1 = (const float*)d_in[3];
  const float* ad1 = (const float*)d_in[4];
  const float* b1  = (const float*)d_in[5];
  const float* bng = (const float*)d_in[6];
  const float* bnb = (const float*)d_in[7];
  const float* bnm = (const float*)d_in[8];
  const float* bnv = (const float*)d_in[9];
  const float* W2  = (const float*)d_in[10];
  const float* as2 = (const float*)d_in[11];
  const float* ad2 = (const float*)d_in[12];
  const float* b2  = (const float*)d_in[13];
  float* out = (float*)d_out;

  int N  = in_sizes[0] / 128;
  int E  = in_sizes[1] / 2;
  int Ep = E + N;
  if (N <= 0 || E <= 0) return;

  // workspace (~43 MB of 256 MB), 256 B-aligned
  char* base = (char*)d_ws;
  size_t off = 0;
  auto alloc = [&](size_t bytes)->char*{
    off = (off + 255) & ~(size_t)255;
    char* q = base + off; off += bytes; return q;
  };
  float* AS     = (float*)alloc((size_t)N*4);
  float* AD     = (float*)alloc((size_t)N*4);
  int*   cnt    = (int*)  alloc((size_t)(N+1)*4);
  int*   offs   = (int*)  alloc((size_t)(N+1)*4);
  int*   cursor = (int*)  alloc((size_t)N*4);
  int*   bsums  = (int*)  alloc(1024);
  int*   csr    = (int*)  alloc((size_t)Ep*4);
  u16*   hb     = (u16*)  alloc((size_t)N*128*2);   // 12.8 MB bf16 gather operand
  float* x2     = (float*)alloc((size_t)N*128*4);   // 25.6 MB

  int n1 = N + 1;
  int zb = (n1 + 255)/256;
  int eb = (Ep + 255)/256;
  int sb = (n1 + 255)/256;
  int gb = (N + 63)/64;   // gemm: 64 rows / block
  int wb = (N + 3)/4;     // aggregate: 4 waves / block

  // CSR prefix (exposed ~20 µs)
  r15_zero <<<zb, 256, 0, stream>>>(cnt, n1);
  r15_hist <<<eb, 256, 0, stream>>>(ei, E, Ep, cnt);
  r15_scan1<<<sb, 256, 0, stream>>>(cnt, n1, offs, bsums);
  r15_scan2<<<1, 256, 0, stream>>>(bsums, sb);
  r15_scan3<<<sb, 256, 0, stream>>>(offs, cnt, bsums, n1, N, offs, cursor);

  // FAT: layer-1 GEMM+dots co-scheduled with CSR fill (independent work)
  r15_gemm_fill<<<gb + eb, 256, 0, stream>>>(x, W1, as1, ad1, hb, AS, AD, N, gb,
                                             ei, E, Ep, cursor, csr);
  // layer 1 aggregate -> relu+BN -> x2
  r15_aggregate<<<wb, 256, 0, stream>>>(hb, AS, AD, offs, csr, b1, bng, bnb, bnm, bnv,
                                        x2, N, 1);
  // layer 2
  r15_gemm     <<<gb, 256, 0, stream>>>(x2, W2, as2, ad2, hb, AS, AD, N);
  r15_aggregate<<<wb, 256, 0, stream>>>(hb, AS, AD, offs, csr, b2, 0, 0, 0, 0,
                                        out, N, 0);
}